// Round 4
// baseline (224.210 us; speedup 1.0000x reference)
//
#include <hip/hip_runtime.h>
#include <cstdint>
#include <cstddef>

#define BD 16
#define SD 4096
#define DD 1024
#define L2E 1.4426950408889634f
#define PREC 1028   // floats per partial record: 1024 o + m + l + pad
#define NCHUNK 64

typedef float f32x4 __attribute__((ext_vector_type(4)));

__device__ __forceinline__ float dot4(f32x4 a, f32x4 b) {
    return fmaf(a.x, b.x, fmaf(a.y, b.y, fmaf(a.z, b.z, a.w * b.w)));
}

// ws layout:
//   int   cnt[BD]                  (64 B, zeroed by ctx_proj each call)
//   float ctilp[BD][4][DD]         (256 KB, e-slice partials of ctx @ W)
//   float partials[BD][NCHUNK][PREC]

// ---------------------------------------------------------------------------
// Kernel 1: e-slice partial of ctil[b,d] = sum_e ctx[b,e] W[e,d].
// grid (4 d-tiles, 16 b, 4 e-slices); 256 thr = 64 d4-lanes x 4 sub-e-groups.
// No atomics, no memset: each block owns ctilp[b][ez][dt*256 .. +256).
// Also resets cnt[b] (runs strictly before flash: separate dispatch).
// ---------------------------------------------------------------------------
__global__ __launch_bounds__(256)
void ctx_proj_kernel(const float* __restrict__ ctx,
                     const float* __restrict__ W,
                     float* __restrict__ ctilp,
                     int* __restrict__ cnt) {
    const int tid = threadIdx.x;
    const int dl  = tid & 63;
    const int eg  = tid >> 6;            // 0..3
    const int dt  = blockIdx.x;          // 0..3
    const int b   = blockIdx.y;          // 0..15
    const int ez  = blockIdx.z;          // 0..3
    const int d4  = dt * 256 + dl * 4;

    if (dt == 0 && ez == 0 && tid == 0) cnt[b] = 0;

    __shared__ float cs[256];
    cs[tid] = ctx[b * DD + ez * 256 + tid];
    __syncthreads();

    f32x4 acc = {0.f, 0.f, 0.f, 0.f};
    const float* cp = cs + eg * 64;
    const float* Wp = W + (size_t)(ez * 256 + eg * 64) * DD + d4;
#pragma unroll 8
    for (int e = 0; e < 64; ++e)
        acc += cp[e] * *(const f32x4*)(Wp + (size_t)e * DD);

    __shared__ f32x4 red[256];
    red[tid] = acc;
    __syncthreads();
    if (tid < 64) {
        f32x4 r = red[tid] + red[64 + tid] + red[128 + tid] + red[192 + tid];
        *(f32x4*)(ctilp + (size_t)(b * 4 + ez) * DD + d4) = r;
    }
}

// ---------------------------------------------------------------------------
// Kernel 2: fused score + online-softmax + weighted accumulation + last-block
// finalize. grid (NCHUNK, B) = 1024 blocks x 4 waves. Ping-pong row buffer
// keeps the next row's 4 NT loads in flight under the dot/shfl/exp chain.
// Branchless rescale (fmax + always-correct), exact in fp.
// ---------------------------------------------------------------------------
__global__ __launch_bounds__(256)
void flash_kernel(const float* __restrict__ values,
                  const float* __restrict__ ctilp,
                  float* __restrict__ partials,
                  int* __restrict__ cnt,
                  float* __restrict__ out) {
    constexpr int ROWS = SD / NCHUNK;    // 64
    const int chunk = blockIdx.x;
    const int b     = blockIdx.y;
    const int r0    = chunk * ROWS;
    const int tid   = threadIdx.x;
    const int wave  = tid >> 6;
    const int lane  = tid & 63;

    // ctil = sum of the 4 e-slice partials (tiny, cache-hit)
    const f32x4* cp0 = (const f32x4*)(ctilp + (size_t)(b * 4 + 0) * DD);
    const f32x4* cp1 = (const f32x4*)(ctilp + (size_t)(b * 4 + 1) * DD);
    const f32x4* cp2 = (const f32x4*)(ctilp + (size_t)(b * 4 + 2) * DD);
    const f32x4* cp3 = (const f32x4*)(ctilp + (size_t)(b * 4 + 3) * DD);
    const f32x4 c0 = cp0[lane]       + cp1[lane]       + cp2[lane]       + cp3[lane];
    const f32x4 c1 = cp0[64 + lane]  + cp1[64 + lane]  + cp2[64 + lane]  + cp3[64 + lane];
    const f32x4 c2 = cp0[128 + lane] + cp1[128 + lane] + cp2[128 + lane] + cp3[128 + lane];
    const f32x4 c3 = cp0[192 + lane] + cp1[192 + lane] + cp2[192 + lane] + cp3[192 + lane];

    f32x4 o0 = {0.f, 0.f, 0.f, 0.f}, o1 = o0, o2 = o0, o3 = o0;
    float m = -1e30f, l = 0.f;

    const f32x4* vb = (const f32x4*)(values + ((size_t)b * SD + r0) * DD);

#define ACCUM(v0, v1, v2, v3) do {                                          \
    float s_ = dot4(v0, c0) + dot4(v1, c1) + dot4(v2, c2) + dot4(v3, c3);   \
    _Pragma("unroll")                                                       \
    for (int off_ = 32; off_ > 0; off_ >>= 1) s_ += __shfl_xor(s_, off_, 64); \
    float mn_   = fmaxf(m, s_);                                             \
    float corr_ = exp2f((m - mn_) * L2E);                                   \
    float pw_   = exp2f((s_ - mn_) * L2E);                                  \
    m = mn_;                                                                \
    l = fmaf(l, corr_, pw_);                                                \
    o0 = o0 * corr_ + pw_ * v0;  o1 = o1 * corr_ + pw_ * v1;                \
    o2 = o2 * corr_ + pw_ * v2;  o3 = o3 * corr_ + pw_ * v3;                \
} while (0)

    const f32x4* p0 = vb + (size_t)wave * (DD / 4);
    f32x4 va0 = __builtin_nontemporal_load(p0 + lane);
    f32x4 va1 = __builtin_nontemporal_load(p0 + 64 + lane);
    f32x4 va2 = __builtin_nontemporal_load(p0 + 128 + lane);
    f32x4 va3 = __builtin_nontemporal_load(p0 + 192 + lane);

#pragma unroll 1
    for (int i = wave + 4; i < ROWS; i += 4) {
        const f32x4* q = vb + (size_t)i * (DD / 4);
        f32x4 n0 = __builtin_nontemporal_load(q + lane);
        f32x4 n1 = __builtin_nontemporal_load(q + 64 + lane);
        f32x4 n2 = __builtin_nontemporal_load(q + 128 + lane);
        f32x4 n3 = __builtin_nontemporal_load(q + 192 + lane);
        ACCUM(va0, va1, va2, va3);
        va0 = n0; va1 = n1; va2 = n2; va3 = n3;
    }
    ACCUM(va0, va1, va2, va3);
#undef ACCUM

    // ---- combine the 4 waves' partials ----
    __shared__ float red_m[4];
    __shared__ float red_l[4];
    __shared__ f32x4 obuf[4][256];

    if (lane == 0) { red_m[wave] = m; red_l[wave] = l; }
    __syncthreads();

    const float M = fmaxf(fmaxf(red_m[0], red_m[1]), fmaxf(red_m[2], red_m[3]));
    const float Lb =
        red_l[0] * exp2f((red_m[0] - M) * L2E) +
        red_l[1] * exp2f((red_m[1] - M) * L2E) +
        red_l[2] * exp2f((red_m[2] - M) * L2E) +
        red_l[3] * exp2f((red_m[3] - M) * L2E);

    const float corr = exp2f((m - M) * L2E);  // wave-uniform
    obuf[wave][lane]       = o0 * corr;
    obuf[wave][64 + lane]  = o1 * corr;
    obuf[wave][128 + lane] = o2 * corr;
    obuf[wave][192 + lane] = o3 * corr;
    __syncthreads();

    f32x4 t = obuf[0][tid] + obuf[1][tid] + obuf[2][tid] + obuf[3][tid];

    float* part = partials + (size_t)(b * NCHUNK + chunk) * PREC;
    ((f32x4*)part)[tid] = t;
    if (tid == 0) { part[1024] = M; part[1025] = Lb; }

    // ---- last block for this b does the cross-chunk combine ----
    __shared__ int amLast;
    __threadfence();
    __syncthreads();
    if (tid == 0) amLast = (atomicAdd(&cnt[b], 1) == NCHUNK - 1);
    __syncthreads();
    if (!amLast) return;
    __threadfence();

    const float* base = partials + (size_t)b * NCHUNK * PREC;
    __shared__ float corr_s[NCHUNK];
    __shared__ float L_s;

    if (tid < 64) {
        float mv = base[(size_t)tid * PREC + 1024];
        float lv = base[(size_t)tid * PREC + 1025];
        float mm = mv;
#pragma unroll
        for (int off = 32; off > 0; off >>= 1) mm = fmaxf(mm, __shfl_xor(mm, off, 64));
        float c = exp2f((mv - mm) * L2E);
        corr_s[tid] = c;
        float lp = c * lv;
#pragma unroll
        for (int off = 32; off > 0; off >>= 1) lp += __shfl_xor(lp, off, 64);
        if (tid == 0) L_s = lp;
    }
    __syncthreads();

    const float inv = 1.0f / L_s;
    f32x4 acc = {0.f, 0.f, 0.f, 0.f};
#pragma unroll 8
    for (int i = 0; i < NCHUNK; ++i)
        acc += corr_s[i] * *(const f32x4*)(base + (size_t)i * PREC + tid * 4);
    *(f32x4*)(out + (size_t)b * DD + tid * 4) = acc * inv;
}

// ---------------------------------------------------------------------------
extern "C" void kernel_launch(void* const* d_in, const int* in_sizes, int n_in,
                              void* d_out, int out_size, void* d_ws, size_t ws_size,
                              hipStream_t stream) {
    const float* values = (const float*)d_in[0];   // [B,S,D]
    const float* ctx    = (const float*)d_in[1];   // [B,D]
    const float* W      = (const float*)d_in[2];   // [D,D]
    // d_in[3] = bias: softmax-shift invariant, dropped.
    float* out = (float*)d_out;                    // [B,D] f32

    int*   cnt      = (int*)d_ws;
    float* ctilp    = (float*)d_ws + 16;                       // 16B-aligned
    float* partials = ctilp + (size_t)BD * 4 * DD;

    ctx_proj_kernel<<<dim3(4, BD, 4), 256, 0, stream>>>(ctx, W, ctilp, cnt);
    flash_kernel<<<dim3(NCHUNK, BD), 256, 0, stream>>>(values, ctilp, partials, cnt, out);
}

// Round 5
// 57.961 us; speedup vs baseline: 3.8683x; 3.8683x over previous
//
#include <hip/hip_runtime.h>
#include <cstdint>
#include <cstddef>

#define BD 16
#define SD 4096
#define DD 1024
#define L2E 1.4426950408889634f
#define PREC 1028   // floats per partial record: 1024 o + m + l + pad
#define NCHUNK 64

typedef float f32x4 __attribute__((ext_vector_type(4)));

__device__ __forceinline__ float dot4(f32x4 a, f32x4 b) {
    return fmaf(a.x, b.x, fmaf(a.y, b.y, fmaf(a.z, b.z, a.w * b.w)));
}

// ws layout:
//   float ctilp[BD][4][DD]           (256 KB, e-slice partials of ctx @ W)
//   float partials[BD][NCHUNK][PREC]

// ---------------------------------------------------------------------------
// Kernel 1: e-slice partial of ctil[b,d] = sum_e ctx[b,e] W[e,d].
// grid (4 d-tiles, 16 b, 4 e-slices); 256 thr = 64 d4-lanes x 4 sub-e-groups.
// No atomics, no memset: each block owns ctilp[b][ez][dt*256 .. +256).
// (bias dropped: softmax-shift invariant per batch)
// ---------------------------------------------------------------------------
__global__ __launch_bounds__(256)
void ctx_proj_kernel(const float* __restrict__ ctx,
                     const float* __restrict__ W,
                     float* __restrict__ ctilp) {
    const int tid = threadIdx.x;
    const int dl  = tid & 63;
    const int eg  = tid >> 6;            // 0..3
    const int dt  = blockIdx.x;          // 0..3
    const int b   = blockIdx.y;          // 0..15
    const int ez  = blockIdx.z;          // 0..3
    const int d4  = dt * 256 + dl * 4;

    __shared__ float cs[256];
    cs[tid] = ctx[b * DD + ez * 256 + tid];
    __syncthreads();

    f32x4 acc = {0.f, 0.f, 0.f, 0.f};
    const float* cp = cs + eg * 64;
    const float* Wp = W + (size_t)(ez * 256 + eg * 64) * DD + d4;
#pragma unroll 8
    for (int e = 0; e < 64; ++e)
        acc += cp[e] * *(const f32x4*)(Wp + (size_t)e * DD);

    __shared__ f32x4 red[256];
    red[tid] = acc;
    __syncthreads();
    if (tid < 64) {
        f32x4 r = red[tid] + red[64 + tid] + red[128 + tid] + red[192 + tid];
        *(f32x4*)(ctilp + (size_t)(b * 4 + ez) * DD + d4) = r;
    }
}

// ---------------------------------------------------------------------------
// Kernel 2: fused score + online-softmax + weighted accumulation, one pass
// over values. grid (NCHUNK, B) = 1024 blocks x 4 waves = 16 waves/CU.
// R3-proven loop shape: plain NT loads, compiler-scheduled pipelining
// (unroll 2), rare branch-based rescale. DO NOT hand-pipeline this loop:
// R4's manual ping-pong + unroll(1) dropped VGPR to 44 and serialized all
// loads (224 us vs 61 us).
// ---------------------------------------------------------------------------
__global__ __launch_bounds__(256)
void flash_kernel(const float* __restrict__ values,
                  const float* __restrict__ ctilp,
                  float* __restrict__ partials) {
    constexpr int ROWS = SD / NCHUNK;    // 64
    const int chunk = blockIdx.x;
    const int b     = blockIdx.y;
    const int r0    = chunk * ROWS;
    const int tid   = threadIdx.x;
    const int wave  = tid >> 6;
    const int lane  = tid & 63;

    // ctil = sum of the 4 e-slice partials (tiny, L2-hit)
    const f32x4* cp0 = (const f32x4*)(ctilp + (size_t)(b * 4 + 0) * DD);
    const f32x4* cp1 = (const f32x4*)(ctilp + (size_t)(b * 4 + 1) * DD);
    const f32x4* cp2 = (const f32x4*)(ctilp + (size_t)(b * 4 + 2) * DD);
    const f32x4* cp3 = (const f32x4*)(ctilp + (size_t)(b * 4 + 3) * DD);
    const f32x4 c0 = cp0[lane]       + cp1[lane]       + cp2[lane]       + cp3[lane];
    const f32x4 c1 = cp0[64 + lane]  + cp1[64 + lane]  + cp2[64 + lane]  + cp3[64 + lane];
    const f32x4 c2 = cp0[128 + lane] + cp1[128 + lane] + cp2[128 + lane] + cp3[128 + lane];
    const f32x4 c3 = cp0[192 + lane] + cp1[192 + lane] + cp2[192 + lane] + cp3[192 + lane];

    f32x4 o0 = {0.f, 0.f, 0.f, 0.f}, o1 = o0, o2 = o0, o3 = o0;
    float m = -1e30f, l = 0.f;

#pragma unroll 2
    for (int i = wave; i < ROWS; i += 4) {
        const f32x4* v4 = (const f32x4*)(values + ((size_t)b * SD + r0 + i) * DD);
        f32x4 v0 = __builtin_nontemporal_load(v4 + lane);
        f32x4 v1 = __builtin_nontemporal_load(v4 + 64 + lane);
        f32x4 v2 = __builtin_nontemporal_load(v4 + 128 + lane);
        f32x4 v3 = __builtin_nontemporal_load(v4 + 192 + lane);

        float s = dot4(v0, c0) + dot4(v1, c1) + dot4(v2, c2) + dot4(v3, c3);
#pragma unroll
        for (int off = 32; off > 0; off >>= 1) s += __shfl_xor(s, off, 64);

        if (s > m) {   // wave-uniform branch, rarely taken after warm-up
            float corr = exp2f((m - s) * L2E);
            m = s;
            l *= corr;
            o0 *= corr; o1 *= corr; o2 *= corr; o3 *= corr;
        }
        float p = exp2f((s - m) * L2E);
        l += p;
        o0 += p * v0; o1 += p * v1; o2 += p * v2; o3 += p * v3;
    }

    // ---- combine the 4 waves' partials ----
    __shared__ float red_m[4];
    __shared__ float red_l[4];
    __shared__ f32x4 obuf[4][256];

    if (lane == 0) { red_m[wave] = m; red_l[wave] = l; }
    __syncthreads();

    const float M = fmaxf(fmaxf(red_m[0], red_m[1]), fmaxf(red_m[2], red_m[3]));
    const float Lb =
        red_l[0] * exp2f((red_m[0] - M) * L2E) +
        red_l[1] * exp2f((red_m[1] - M) * L2E) +
        red_l[2] * exp2f((red_m[2] - M) * L2E) +
        red_l[3] * exp2f((red_m[3] - M) * L2E);

    const float corr = exp2f((m - M) * L2E);  // wave-uniform
    obuf[wave][lane]       = o0 * corr;
    obuf[wave][64 + lane]  = o1 * corr;
    obuf[wave][128 + lane] = o2 * corr;
    obuf[wave][192 + lane] = o3 * corr;
    __syncthreads();

    f32x4 t = obuf[0][tid] + obuf[1][tid] + obuf[2][tid] + obuf[3][tid];

    float* part = partials + (size_t)(b * NCHUNK + chunk) * PREC;
    ((f32x4*)part)[tid] = t;
    if (tid == 0) { part[1024] = M; part[1025] = Lb; }
}

// ---------------------------------------------------------------------------
// Kernel 3: combine NCHUNK partials -> out[b,:]. grid (4 d-tiles, B).
// ---------------------------------------------------------------------------
__global__ __launch_bounds__(256)
void finalize_kernel(const float* __restrict__ partials,
                     float* __restrict__ out) {
    const int dt  = blockIdx.x;       // 0..3
    const int b   = blockIdx.y;       // 0..15
    const int tid = threadIdx.x;
    const float* base = partials + (size_t)b * NCHUNK * PREC;

    __shared__ float corr_s[NCHUNK];
    __shared__ float L_s;

    if (tid < 64) {
        float mv = base[(size_t)tid * PREC + 1024];
        float lv = base[(size_t)tid * PREC + 1025];
        float mm = mv;
#pragma unroll
        for (int off = 32; off > 0; off >>= 1) mm = fmaxf(mm, __shfl_xor(mm, off, 64));
        float c = exp2f((mv - mm) * L2E);
        corr_s[tid] = c;
        float lp = c * lv;
#pragma unroll
        for (int off = 32; off > 0; off >>= 1) lp += __shfl_xor(lp, off, 64);
        if (tid == 0) L_s = lp;
    }
    __syncthreads();

    const float inv = 1.0f / L_s;
    const int d = dt * 256 + tid;
    float acc = 0.f;
#pragma unroll 16
    for (int i = 0; i < NCHUNK; ++i)
        acc = fmaf(corr_s[i], base[(size_t)i * PREC + d], acc);
    out[(size_t)b * DD + d] = acc * inv;
}

// ---------------------------------------------------------------------------
extern "C" void kernel_launch(void* const* d_in, const int* in_sizes, int n_in,
                              void* d_out, int out_size, void* d_ws, size_t ws_size,
                              hipStream_t stream) {
    const float* values = (const float*)d_in[0];   // [B,S,D]
    const float* ctx    = (const float*)d_in[1];   // [B,D]
    const float* W      = (const float*)d_in[2];   // [D,D]
    // d_in[3] = bias: softmax-shift invariant, dropped.
    float* out = (float*)d_out;                    // [B,D] f32

    float* ctilp    = (float*)d_ws;                // BD*4*DD floats
    float* partials = ctilp + (size_t)BD * 4 * DD; // BD*NCHUNK*PREC floats

    ctx_proj_kernel<<<dim3(4, BD, 4), 256, 0, stream>>>(ctx, W, ctilp);
    flash_kernel<<<dim3(NCHUNK, BD), 256, 0, stream>>>(values, ctilp, partials);
    finalize_kernel<<<dim3(4, BD), 256, 0, stream>>>(partials, out);
}